// Round 2
// 558.725 us; speedup vs baseline: 1.1029x; 1.1029x over previous
//
#include <hip/hip_runtime.h>
#include <math.h>

// Spherical harmonics l=0..3 of normalized 3-vectors, component normalization.
// Memory-bound: 96 MB read + 512 MB write = 608 MB => ~97 us floor @ 6.3 TB/s.
//
// Round-0 kernel: per-thread AoS writes => lane strides of 48/80/112 B on the
// float4 stores => each wave store fragments into ~48 partial-line transactions
// => ~2.1 TB/s effective. This version stages outputs in LDS (conflict-free
// strides 3/5/7: gcd with 32 banks == 1) and copies out with lane-contiguous
// nontemporal float4 stores so every global access is perfectly coalesced.
// (Round-1 resubmit: Round-1 bench was an infra failure, no kernel signal.)

typedef float f32x4 __attribute__((ext_vector_type(4)));

#define BLOCK 256
#define VPB   512   // vectors per block (2 per thread); LDS = 15*512*4 = 30 KB

__device__ __forceinline__ void compute_sh(float px, float py, float pz,
                                           float* __restrict__ s1,
                                           float* __restrict__ s2,
                                           float* __restrict__ s3) {
    float sn = px * px + py * py + pz * pz;
    // eps==0 path: zero vector -> u = 0 -> all higher-l outputs 0.
    float inv = (sn == 0.0f) ? 0.0f : rsqrtf(sn);
    float vx = px * inv, vy = py * inv, vz = pz * inv;

    const float SQ3 = 1.7320508075688772f;   // sqrt(3)
    const float S15 = 3.872983346207417f;    // sqrt(15)
    const float SQ5 = 2.23606797749979f;     // sqrt(5)
    const float C42_6 = 1.0801234497346435f; // sqrt(42)/6
    const float C168_8 = 1.6201851746019651f;// sqrt(168)/8
    const float S7 = 2.6457513110645907f;    // sqrt(7)

    float x2 = vx * vx, y2 = vy * vy, z2 = vz * vz;
    float x2z2 = x2 + z2;

    s1[0] = SQ3 * vx;
    s1[1] = SQ3 * vy;
    s1[2] = SQ3 * vz;

    float sh2_0 = S15 * vx * vz;
    float sh2_4 = 0.5f * S15 * (z2 - x2);
    s2[0] = sh2_0;
    s2[1] = S15 * vx * vy;
    s2[2] = SQ5 * (y2 - 0.5f * x2z2);
    s2[3] = S15 * vy * vz;
    s2[4] = sh2_4;

    float q = 4.0f * y2 - x2z2;
    s3[0] = C42_6 * (sh2_0 * vz + sh2_4 * vx);
    s3[1] = S7 * sh2_0 * vy;
    s3[2] = C168_8 * q * vx;
    s3[3] = 0.5f * S7 * vy * (2.0f * y2 - 3.0f * x2z2);
    s3[4] = C168_8 * vz * q;
    s3[5] = S7 * sh2_4 * vy;
    s3[6] = C42_6 * (sh2_4 * vz - sh2_0 * vx);
}

__global__ __launch_bounds__(BLOCK) void sh_kernel(const float* __restrict__ x,
                                                   float* __restrict__ out,
                                                   long long nvec) {
    // LDS layout: [ 3*VPB floats sh1 | 5*VPB floats sh2 | 7*VPB floats sh3 ]
    __shared__ float lds[15 * VPB];
    float* lds1 = lds;                 // 1536 floats
    float* lds2 = lds + 3 * VPB;       // 2560 floats
    float* lds3 = lds + 8 * VPB;       // 3584 floats

    const int lt = threadIdx.x;
    const long long base = (long long)blockIdx.x * VPB;

    float* out0 = out;                 // N  floats
    float* out1 = out + nvec;          // 3N floats
    float* out2 = out + 4 * nvec;      // 5N floats
    float* out3 = out + 9 * nvec;      // 7N floats

    long long cnt = nvec - base;

    if (cnt >= VPB) {
        // ---- compute 2 vectors/thread; vectors lt and lt+256 of this block.
        // Input: scalar loads, lane stride 12 B -> each instruction covers a
        // contiguous 768 B window, fully consumed across the 3 components
        // (L1 absorbs the per-line re-touches; reads are 96/608 of traffic).
        const float* xin = x + 3 * base;
#pragma unroll
        for (int k = 0; k < 2; ++k) {
            const int v = lt + BLOCK * k;
            float s1[3], s2[5], s3[7];
            compute_sh(xin[3 * v + 0], xin[3 * v + 1], xin[3 * v + 2],
                       s1, s2, s3);
            // LDS scatter in FINAL global layout. Lane strides 3/5/7 floats:
            // gcd(.,32)==1 -> exactly 2 lanes per bank -> conflict-free.
#pragma unroll
            for (int c = 0; c < 3; ++c) lds1[3 * v + c] = s1[c];
#pragma unroll
            for (int c = 0; c < 5; ++c) lds2[5 * v + c] = s2[c];
#pragma unroll
            for (int c = 0; c < 7; ++c) lds3[7 * v + c] = s3[c];
        }
        __syncthreads();

        // ---- sh0: VPB ones, written directly (base%4==0 -> 16B aligned)
        if (lt < VPB / 4) {
            f32x4 ones = {1.0f, 1.0f, 1.0f, 1.0f};
            __builtin_nontemporal_store(ones, (f32x4*)(out0 + base) + lt);
        }

        // ---- coalesced copy-out: lane-contiguous float4 streaming stores.
        // Uniform full-BLOCK iterations + one guarded remainder wavefront
        // (trip counts: 384 = 256+128, 640 = 2*256+128, 896 = 3*256+128).
        if ((nvec & 3) == 0) {   // stream bases out+{1,4,9}*nvec 16B-aligned
            const f32x4* l1 = (const f32x4*)lds1;
            const f32x4* l2 = (const f32x4*)lds2;
            const f32x4* l3 = (const f32x4*)lds3;
            f32x4* g1 = (f32x4*)(out1 + 3 * base);
            f32x4* g2 = (f32x4*)(out2 + 5 * base);
            f32x4* g3 = (f32x4*)(out3 + 7 * base);

            __builtin_nontemporal_store(l1[lt], g1 + lt);                  // 0..255
            if (lt < 128)
                __builtin_nontemporal_store(l1[256 + lt], g1 + 256 + lt);  // 256..383

#pragma unroll
            for (int k = 0; k < 2; ++k)
                __builtin_nontemporal_store(l2[k * 256 + lt], g2 + k * 256 + lt);
            if (lt < 128)
                __builtin_nontemporal_store(l2[512 + lt], g2 + 512 + lt);  // 512..639

#pragma unroll
            for (int k = 0; k < 3; ++k)
                __builtin_nontemporal_store(l3[k * 256 + lt], g3 + k * 256 + lt);
            if (lt < 128)
                __builtin_nontemporal_store(l3[768 + lt], g3 + 768 + lt);  // 768..895
        } else {
            // generality fallback: scalar coalesced copy (not taken for N=8e6)
            for (int i = lt; i < 3 * VPB; i += BLOCK) out1[3 * base + i] = lds1[i];
            for (int i = lt; i < 5 * VPB; i += BLOCK) out2[5 * base + i] = lds2[i];
            for (int i = lt; i < 7 * VPB; i += BLOCK) out3[7 * base + i] = lds3[i];
        }
    } else {
        // ---- partial tail block (not taken for N=8e6: 8e6 = 512*15625)
        for (long long i = base + lt; i < nvec; i += BLOCK) {
            float s1[3], s2[5], s3[7];
            compute_sh(x[3 * i], x[3 * i + 1], x[3 * i + 2], s1, s2, s3);
            out0[i] = 1.0f;
            for (int k = 0; k < 3; ++k) out1[3 * i + k] = s1[k];
            for (int k = 0; k < 5; ++k) out2[5 * i + k] = s2[k];
            for (int k = 0; k < 7; ++k) out3[7 * i + k] = s3[k];
        }
    }
}

extern "C" void kernel_launch(void* const* d_in, const int* in_sizes, int n_in,
                              void* d_out, int out_size, void* d_ws, size_t ws_size,
                              hipStream_t stream) {
    const float* x = (const float*)d_in[0];
    float* out = (float*)d_out;
    long long nvec = (long long)in_sizes[0] / 3;
    long long grid = (nvec + VPB - 1) / VPB;
    sh_kernel<<<dim3((unsigned)grid), BLOCK, 0, stream>>>(x, out, nvec);
}